// Round 4
// baseline (294.075 us; speedup 1.0000x reference)
//
#include <hip/hip_runtime.h>

#define S_LEN 512
#define H_DIM 128
#define C_DIM 10

typedef __attribute__((ext_vector_type(8))) short short8;
typedef __attribute__((ext_vector_type(4))) float f32x4;

__device__ __forceinline__ unsigned short f2bf(float f) {
    union { float f; unsigned u; } v; v.f = f;
    return (unsigned short)((v.u + 0x7FFFu + ((v.u >> 16) & 1u)) >> 16);
}

__device__ __forceinline__ float fast_sigmoid(float x) {
    float e = __builtin_amdgcn_exp2f(-1.4426950408889634f * x);
    return __builtin_amdgcn_rcpf(1.0f + e);
}
__device__ __forceinline__ float fast_tanh(float x) {
    float e = __builtin_amdgcn_exp2f(2.8853900817779268f * x);  // e^{2x}
    return 1.0f - 2.0f * __builtin_amdgcn_rcpf(e + 1.0f);
}

// 256 blocks x 256 threads (4 waves, 1 wave/SIMD), 4 batch rows/block at
// MFMA M-rows 4b. Wave w owns h-cols [32w, 32w+32) for all 4 gates
// (2 N-tiles x 4 gates = 8 MFMA tiles, K=128 as 4 chained 16x16x32).
// Chain-shortening vs R3: 4-wave barrier (was 8), 1 wave/SIMD (no issue
// contention), bias+x-projection seeded into MFMA C elem 0 (off-chain),
// per-lane cvt_pk + 2x ds_write_b16 (no shfl on the chain).
// h lives in LDS in A-fragment order (conflict-free, verified R3: 45K).
__global__ __launch_bounds__(256, 1) void lstm_fused(
    const float* __restrict__ x,
    const float* __restrict__ Wgx, const float* __restrict__ Wgh,
    const float* __restrict__ Wix, const float* __restrict__ Wih,
    const float* __restrict__ Wfx, const float* __restrict__ Wfh,
    const float* __restrict__ Wox, const float* __restrict__ Woh,
    const float* __restrict__ Wph,
    const float* __restrict__ bg, const float* __restrict__ bi,
    const float* __restrict__ bff, const float* __restrict__ bo,
    const float* __restrict__ bp,
    float* __restrict__ out)
{
    __shared__ float xr[4][516];                                       // x transposed, padded
    __shared__ __attribute__((aligned(16))) unsigned short hb[2][512]; // h bf16, A-frag order
    __shared__ float hfin[4][H_DIM];
    __shared__ float wls[H_DIM * C_DIM];

    const int tid  = threadIdx.x;
    const int lane = tid & 63;
    const int w    = tid >> 6;        // wave 0..3
    const int b0   = blockIdx.x * 4;  // batch row base

    // ---- stage x transposed (coalesced) ----
    {
        const float* xp = x + b0 * S_LEN;
        #pragma unroll
        for (int r = 0; r < 4; ++r) {
            xr[r][tid]       = xp[r * S_LEN + tid];
            xr[r][tid + 256] = xp[r * S_LEN + tid + 256];
        }
    }
    ((unsigned*)hb)[tid] = 0;   // zero hb[0] (1024 B)

    const int jl = lane & 15;
    const int kg = lane >> 4;         // batch row (0..3)
    const int c0 = w * 32 + jl;       // first owned h-col
    // second owned h-col = c0 + 16

    // ---- Wh into registers as B-fragments (bf16) ----
    // B-frag lane l elem e: k = 32*kk + 8*(l>>4) + e, n = l&15
    const float* WhA[4] = { Wgh, Wih, Wfh, Woh };
    short8 bfrag[2][4][4];
    #pragma unroll
    for (int n = 0; n < 2; ++n) {
        #pragma unroll
        for (int g = 0; g < 4; ++g) {
            #pragma unroll
            for (int kk = 0; kk < 4; ++kk) {
                const float* src = WhA[g] + (kk * 32 + kg * 8) * H_DIM + (w * 32 + 16 * n + jl);
                short8 v;
                #pragma unroll
                for (int e = 0; e < 8; ++e) v[e] = (short)f2bf(src[e * H_DIM]);
                bfrag[n][g][kk] = v;
            }
        }
    }
    // per-lane x-projection weights/biases for both owned cols
    float wxv[2][4], bv[2][4];
    {
        const float* WxA[4] = { Wgx, Wix, Wfx, Wox };
        const float* bA[4]  = { bg,  bi,  bff, bo  };
        #pragma unroll
        for (int n = 0; n < 2; ++n) {
            #pragma unroll
            for (int g = 0; g < 4; ++g) {
                wxv[n][g] = WxA[g][c0 + 16 * n];
                bv[n][g]  = bA[g][c0 + 16 * n];
            }
        }
    }

    // A-frag read: active lanes lane%4==0, q=lane/4 -> byte q*16 + kk*256
    const bool aActive = (lane & 3) == 0;
    const int  abase   = (lane >> 2) * 16;
    // h-write: (batch kg, col c) at byte (c>>3)*64 + kg*16 + (c&7)*2
    const int  wbyte0  = (4 * w + (jl >> 3)) * 64 + kg * 16 + (jl & 7) * 2;  // +128 for col+16

    float cst[2] = { 0.f, 0.f };
    float hcv[2] = { 0.f, 0.f };

    short8 afr[4];
    #pragma unroll
    for (int kk = 0; kk < 4; ++kk) afr[kk] = short8{0,0,0,0,0,0,0,0};

    f32x4 acc[2][4];
    #pragma unroll
    for (int n = 0; n < 2; ++n)
        #pragma unroll
        for (int g = 0; g < 4; ++g) acc[n][g] = f32x4{0.f,0.f,0.f,0.f};

    __syncthreads();

    unsigned short* const hp[2] = { &hb[0][0], &hb[1][0] };

    for (int t4 = 0; t4 < S_LEN; t4 += 4) {
        const f32x4 xq = *(const f32x4*)&xr[kg][t4];
        #pragma unroll
        for (int s = 0; s < 4; ++s) {
            const unsigned short* src = hp[s & 1];
            unsigned short*       dst = hp[(s & 1) ^ 1];
            const float xv = xq[s];

            // seed C elem0 with x-projection + bias (off the LDS->MFMA chain).
            // elems 1..3 correspond to zero A-rows: they stay constant.
            #pragma unroll
            for (int n = 0; n < 2; ++n)
                #pragma unroll
                for (int g = 0; g < 4; ++g)
                    acc[n][g][0] = __builtin_fmaf(xv, wxv[n][g], bv[n][g]);

            if (aActive) {
                const char* base = (const char*)src + abase;
                #pragma unroll
                for (int kk = 0; kk < 4; ++kk)
                    afr[kk] = *(const short8*)(base + kk * 256);
            }

            #pragma unroll
            for (int kk = 0; kk < 4; ++kk)
                #pragma unroll
                for (int n = 0; n < 2; ++n)
                    #pragma unroll
                    for (int g = 0; g < 4; ++g)
                        acc[n][g] = __builtin_amdgcn_mfma_f32_16x16x32_bf16(
                                        afr[kk], bfrag[n][g][kk], acc[n][g], 0, 0, 0);

            #pragma unroll
            for (int n = 0; n < 2; ++n) {
                const float tg = fast_tanh(acc[n][0][0]);
                const float si = fast_sigmoid(acc[n][1][0]);
                const float sf = fast_sigmoid(acc[n][2][0]);
                const float so = fast_sigmoid(acc[n][3][0]);
                const float cn = __builtin_fmaf(cst[n], sf, tg * si);
                cst[n] = cn;
                const float hn = fast_tanh(cn) * so;
                hcv[n] = hn;
                unsigned pk;
                asm("v_cvt_pk_bf16_f32 %0, %1, %2" : "=v"(pk) : "v"(hn), "v"(hn));
                *(unsigned short*)((char*)dst + wbyte0 + n * 128) = (unsigned short)pk;
            }
            __syncthreads();
        }
    }

    // ---- epilogue: logits = h_last @ W_ph + b_p ----
    hfin[kg][c0]      = hcv[0];
    hfin[kg][c0 + 16] = hcv[1];
    for (int i = tid; i < H_DIM * C_DIM; i += 256) wls[i] = Wph[i];
    __syncthreads();

    if (tid < 4 * C_DIM) {
        const int b = tid / C_DIM, cc = tid % C_DIM;
        float s = bp[cc];
        #pragma unroll 8
        for (int k = 0; k < H_DIM; ++k) s += hfin[b][k] * wls[k * C_DIM + cc];
        out[(b0 + b) * C_DIM + cc] = s;
    }
}

extern "C" void kernel_launch(void* const* d_in, const int* in_sizes, int n_in,
                              void* d_out, int out_size, void* d_ws, size_t ws_size,
                              hipStream_t stream) {
    const float* x   = (const float*)d_in[0];
    const float* Wgx = (const float*)d_in[1];
    const float* Wgh = (const float*)d_in[2];
    const float* Wix = (const float*)d_in[3];
    const float* Wih = (const float*)d_in[4];
    const float* Wfx = (const float*)d_in[5];
    const float* Wfh = (const float*)d_in[6];
    const float* Wox = (const float*)d_in[7];
    const float* Woh = (const float*)d_in[8];
    const float* Wph = (const float*)d_in[9];
    const float* bg  = (const float*)d_in[10];
    const float* bi  = (const float*)d_in[11];
    const float* bf  = (const float*)d_in[12];
    const float* bo  = (const float*)d_in[13];
    const float* bp  = (const float*)d_in[14];
    float* out = (float*)d_out;

    lstm_fused<<<dim3(256), dim3(256), 0, stream>>>(
        x, Wgx, Wgh, Wix, Wih, Wfx, Wfh, Wox, Woh, Wph,
        bg, bi, bf, bo, bp, out);
}

// Round 5
// 252.774 us; speedup vs baseline: 1.1634x; 1.1634x over previous
//
#include <hip/hip_runtime.h>

#define S_LEN 512
#define H_DIM 128
#define C_DIM 10

typedef __attribute__((ext_vector_type(8))) short short8;
typedef __attribute__((ext_vector_type(4))) float f32x4;

__device__ __forceinline__ unsigned short f2bf(float f) {
    union { float f; unsigned u; } v; v.f = f;
    return (unsigned short)((v.u + 0x7FFFu + ((v.u >> 16) & 1u)) >> 16);
}

__device__ __forceinline__ float fast_sigmoid(float x) {
    float e = __builtin_amdgcn_exp2f(-1.4426950408889634f * x);
    return __builtin_amdgcn_rcpf(1.0f + e);
}
__device__ __forceinline__ float fast_tanh(float x) {
    float e = __builtin_amdgcn_exp2f(2.8853900817779268f * x);  // e^{2x}
    return 1.0f - 2.0f * __builtin_amdgcn_rcpf(e + 1.0f);
}

// R2 skeleton (best: 218us): 256 blocks x 512 threads (8 waves, 2/SIMD),
// 4 batch rows/block at MFMA M-rows 4b, wave w owns cols [16w,16w+16) of
// all 4 gates (16 MFMA/wave/step, 1 LSTM cell per lane).
// R5 chain cuts: depth-1 MFMA (4 independent accs/gate + add tree, removes
// 3 dependent MFMA latencies), branch-free broadcast A-reads (4 lanes/addr
// = free LDS broadcast, no exec-mask ops), A-frag-order h layout
// (conflict-free, R3-verified), 1-op cvt_pk bf16 h-write.
__global__ __launch_bounds__(512, 1) void lstm_fused(
    const float* __restrict__ x,
    const float* __restrict__ Wgx, const float* __restrict__ Wgh,
    const float* __restrict__ Wix, const float* __restrict__ Wih,
    const float* __restrict__ Wfx, const float* __restrict__ Wfh,
    const float* __restrict__ Wox, const float* __restrict__ Woh,
    const float* __restrict__ Wph,
    const float* __restrict__ bg, const float* __restrict__ bi,
    const float* __restrict__ bff, const float* __restrict__ bo,
    const float* __restrict__ bp,
    float* __restrict__ out)
{
    __shared__ float xr[4][516];                                       // x transposed, padded
    __shared__ __attribute__((aligned(16))) unsigned short hb[2][512]; // h bf16, A-frag order
    __shared__ float hfin[4][H_DIM];

    const int tid  = threadIdx.x;
    const int lane = tid & 63;
    const int w    = tid >> 6;        // wave 0..7
    const int b0   = blockIdx.x * 4;  // batch row base

    // ---- stage x transposed (coalesced) ----
    {
        const float* xp = x + b0 * S_LEN;
        #pragma unroll
        for (int r = 0; r < 4; ++r) xr[r][tid] = xp[r * S_LEN + tid];
    }
    ((unsigned short*)hb)[tid] = 0;   // zero hb[0]

    const int jl = lane & 15;
    const int kg = lane >> 4;         // 0..3
    const int j  = w * 16 + jl;       // owned h-col

    // ---- Wh into registers as B-fragments (bf16) ----
    // B-frag lane l elem e: k = 32*kk + 8*(l>>4) + e, n = l&15
    const float* WhA[4] = { Wgh, Wih, Wfh, Woh };
    short8 bfrag[4][4];
    #pragma unroll
    for (int g = 0; g < 4; ++g) {
        #pragma unroll
        for (int kk = 0; kk < 4; ++kk) {
            const float* src = WhA[g] + (kk * 32 + kg * 8) * H_DIM + j;
            short8 v;
            #pragma unroll
            for (int e = 0; e < 8; ++e) v[e] = (short)f2bf(src[e * H_DIM]);
            bfrag[g][kk] = v;
        }
    }
    const float wxv[4] = { Wgx[j], Wix[j], Wfx[j], Wox[j] };
    const float bv[4]  = { bg[j],  bi[j],  bff[j], bo[j]  };

    // Broadcast A-read: every lane reads; lanes sharing (batch,e-block) hit
    // the same address (LDS broadcast, free). Invalid M-rows get neighbor
    // batch data -> pollutes only unused C rows.
    const int abase = ((lane & 15) >> 2) * 16 + (lane >> 4) * 64;  // byte, +kk*256
    // h-write (batch kg, col j): ushort idx in A-frag order
    const int widx  = kg * 8 + ((j >> 3) & 3) * 32 + (j >> 5) * 128 + (j & 7);

    float cst  = 0.f;
    float hcur = 0.f;
    const f32x4 zf = { 0.f, 0.f, 0.f, 0.f };

    __syncthreads();

    unsigned short* const h0 = &hb[0][0];
    unsigned short* const h1 = &hb[1][0];

    auto step = [&](const unsigned short* src, unsigned short* dst, float xv) {
        // off-chain: seeds (x-projection + bias)
        float seed[4];
        #pragma unroll
        for (int g = 0; g < 4; ++g) seed[g] = __builtin_fmaf(xv, wxv[g], bv[g]);

        const char* base = (const char*)src + abase;
        short8 afr[4];
        #pragma unroll
        for (int kk = 0; kk < 4; ++kk)
            afr[kk] = *(const short8*)(base + kk * 256);

        // depth-1: 16 independent MFMAs
        f32x4 r[4][4];
        #pragma unroll
        for (int kk = 0; kk < 4; ++kk)
            #pragma unroll
            for (int g = 0; g < 4; ++g)
                r[g][kk] = __builtin_amdgcn_mfma_f32_16x16x32_bf16(
                               afr[kk], bfrag[g][kk], zf, 0, 0, 0);

        float pre[4];
        #pragma unroll
        for (int g = 0; g < 4; ++g) {
            const float t01 = r[g][0][0] + r[g][1][0];
            const float t23 = r[g][2][0] + (r[g][3][0] + seed[g]);
            pre[g] = t01 + t23;
        }

        const float tg = fast_tanh(pre[0]);
        const float si = fast_sigmoid(pre[1]);
        const float sf = fast_sigmoid(pre[2]);
        const float so = fast_sigmoid(pre[3]);
        const float cn = __builtin_fmaf(cst, sf, tg * si);
        cst  = cn;
        const float hn = fast_tanh(cn) * so;
        hcur = hn;
        unsigned pk;
        asm("v_cvt_pk_bf16_f32 %0, %1, %2" : "=v"(pk) : "v"(hn), "v"(hn));
        dst[widx] = (unsigned short)pk;
        __syncthreads();
    };

    for (int t4 = 0; t4 < S_LEN; t4 += 4) {
        const f32x4 xq = *(const f32x4*)&xr[kg][t4];
        step(h0, h1, xq[0]);
        step(h1, h0, xq[1]);
        step(h0, h1, xq[2]);
        step(h1, h0, xq[3]);
    }

    // ---- epilogue: logits = h_last @ W_ph + b_p ----
    hfin[kg][j] = hcur;
    __syncthreads();

    if (tid < 4 * C_DIM) {
        const int b = tid / C_DIM, cc = tid % C_DIM;
        float s = bp[cc];
        #pragma unroll 8
        for (int k = 0; k < H_DIM; ++k) s += hfin[b][k] * Wph[k * C_DIM + cc];
        out[(b0 + b) * C_DIM + cc] = s;
    }
}

extern "C" void kernel_launch(void* const* d_in, const int* in_sizes, int n_in,
                              void* d_out, int out_size, void* d_ws, size_t ws_size,
                              hipStream_t stream) {
    const float* x   = (const float*)d_in[0];
    const float* Wgx = (const float*)d_in[1];
    const float* Wgh = (const float*)d_in[2];
    const float* Wix = (const float*)d_in[3];
    const float* Wih = (const float*)d_in[4];
    const float* Wfx = (const float*)d_in[5];
    const float* Wfh = (const float*)d_in[6];
    const float* Wox = (const float*)d_in[7];
    const float* Woh = (const float*)d_in[8];
    const float* Wph = (const float*)d_in[9];
    const float* bg  = (const float*)d_in[10];
    const float* bi  = (const float*)d_in[11];
    const float* bf  = (const float*)d_in[12];
    const float* bo  = (const float*)d_in[13];
    const float* bp  = (const float*)d_in[14];
    float* out = (float*)d_out;

    lstm_fused<<<dim3(256), dim3(512), 0, stream>>>(
        x, Wgx, Wgh, Wix, Wih, Wfx, Wfh, Wox, Woh, Wph,
        bg, bi, bf, bo, bp, out);
}